// Round 11
// baseline (297.698 us; speedup 1.0000x reference)
//
#include <hip/hip_runtime.h>
#include <hip/hip_bf16.h>

#define N_NODES 32768
#define N_EDGES 524288
#define B_GRAPHS 512

typedef __attribute__((ext_vector_type(8))) short sh8;    // 8 bf16 (4 VGPR) MFMA operand
typedef __attribute__((ext_vector_type(4))) float f32x4;  // MFMA accumulator

// ---------------- bf16 helpers ----------------
__device__ __forceinline__ unsigned short f2b(float f) {
    unsigned int u = __float_as_uint(f);
    return (unsigned short)((u + 0x7FFFu + ((u >> 16) & 1u)) >> 16);
}
__device__ __forceinline__ float blo(unsigned int u) { return __uint_as_float(u << 16); }
__device__ __forceinline__ float bhi(unsigned int u) { return __uint_as_float(u & 0xFFFF0000u); }
__device__ __forceinline__ float gelu_exact(float z) {
    return 0.5f * z * (1.0f + erff(z * 0.70710678118654752440f));
}

#define PREP_BLOCKS 896   // 7*32768/256
#define BX_BLOCKS 4096    // N_NODES*32/256

// ---------------- fused prep: weight transpose/bf16 + deg zero + build_x ----------------
__global__ __launch_bounds__(256) void k_prep(const float* __restrict__ W1,
                                              const float* __restrict__ W2,
                                              const float* __restrict__ gW1,
                                              const float* __restrict__ logits,
                                              const int* __restrict__ feat,
                                              const float* __restrict__ aemb,
                                              unsigned short* __restrict__ W1T,
                                              unsigned short* __restrict__ W2T,
                                              unsigned short* __restrict__ gW1T,
                                              int* __restrict__ deg,
                                              float* __restrict__ x,
                                              unsigned short* __restrict__ xb) {
    int bb = blockIdx.x;
    if (bb < PREP_BLOCKS) {
        int tid = bb * 256 + threadIdx.x;   // 7*32768 total
        if (tid < N_NODES) deg[tid] = 0;    // k_deg runs after on same stream
        int m = tid >> 15, i = tid & 32767;
        if (m < 3) {
            int r = i >> 8, c = i & 255;
            W1T[m * 32768 + c * 128 + r] = f2b(W1[m * 32768 + i]);   // [n=256][k=128]
        } else if (m < 6) {
            int mm = m - 3;
            int r = i >> 7, c = i & 127;
            W2T[mm * 32768 + c * 256 + r] = f2b(W2[mm * 32768 + i]); // [n=128][k=256]
        } else {
            int r = i >> 8, c = i & 255;
            gW1T[c * 128 + r] = f2b(gW1[i]);                         // [n=256][k=128]
        }
    } else {
        // build_x: x = logits[mask] + atom_emb[feat]  (fp32 master + bf16 shadow)
        int idx = (bb - PREP_BLOCKS) * 256 + threadIdx.x;   // float4 id, N_NODES*32 total
        int n = idx >> 5, c = idx & 31;
        int srow = ((n >> 6) << 7) + (n & 63);              // analytic nonzero(mask) index
        float4 lv = ((const float4*)logits)[srow * 32 + c];
        float4 av = ((const float4*)aemb)[feat[n] * 32 + c];
        float4 o;
        o.x = lv.x + av.x; o.y = lv.y + av.y; o.z = lv.z + av.z; o.w = lv.w + av.w;
        ((float4*)x)[idx] = o;
        ushort4 ob;
        ob.x = f2b(o.x); ob.y = f2b(o.y); ob.z = f2b(o.z); ob.w = f2b(o.w);
        ((ushort4*)xb)[idx] = ob;
    }
}

// ---------------- CSR build ----------------
__global__ void k_deg(const int* __restrict__ dst, int* __restrict__ deg) {
    int e = blockIdx.x * blockDim.x + threadIdx.x;
    if (e < N_EDGES) atomicAdd(&deg[dst[e]], 1);
}

__global__ __launch_bounds__(1024) void k_scan(const int* __restrict__ deg,
                                               int* __restrict__ offs,
                                               int* __restrict__ cursor) {
    int tid = threadIdx.x;
    int lane = tid & 63, wid = tid >> 6;
    int base = tid * 32;
    int pref[32];
    int run = 0;
    #pragma unroll
    for (int i = 0; i < 32; i++) { pref[i] = run; run += deg[base + i]; }
    int s = run;
    for (int m = 1; m < 64; m <<= 1) { int t = __shfl_up(s, m); if (lane >= m) s += t; }
    __shared__ int wsum[16];
    if (lane == 63) wsum[wid] = s;
    __syncthreads();
    if (tid < 16) {
        int v = wsum[tid];
        for (int m = 1; m < 16; m <<= 1) { int t = __shfl_up(v, m, 16); if (tid >= m) v += t; }
        wsum[tid] = v;
    }
    __syncthreads();
    int wbase = wid ? wsum[wid - 1] : 0;
    int ebase = wbase + (s - run);
    #pragma unroll
    for (int i = 0; i < 32; i++) {
        int o = ebase + pref[i];
        offs[base + i] = o;
        cursor[base + i] = o;
    }
    if (tid == 1023) offs[N_NODES] = ebase + run;
}

__global__ void k_scatter(const int* __restrict__ src, const int* __restrict__ dst,
                          const int* __restrict__ attr, int* __restrict__ cursor,
                          int* __restrict__ csr) {
    int e = blockIdx.x * blockDim.x + threadIdx.x;
    if (e < N_EDGES) {
        int p = atomicAdd(&cursor[dst[e]], 1);
        csr[p] = src[e] | (attr[e] << 16);
    }
}

// ---------------- per-node aggregation: quarter-wave uint4 gathers, 16-deep batches ----------------
// One wave = one node. Quarter-wave qd (16 lanes x uint4 = 256B) gathers edges i ≡ qd
// (mod 4): half the VMEM instructions of the uint2 half-wave scheme and up to 64 edge
// gathers in flight per wave (vs 16). All shfl broadcasts are WAVE-UNIFORM (bound nq0,
// clamped source lane; adds predicated by per-quarter count nql — round-7 lesson:
// shfl reads garbage from exec-inactive source lanes). Quarter partial sums combine
// via shfl_xor(16,32): (q0+q1)+(q2+q3). fp32 reorder vs the old even/odd split is
// ~1e-5 abs — negligible against aggb's bf16 rounding.
__global__ __launch_bounds__(256) void k_agg(const unsigned short* __restrict__ xb,
                                             const int* __restrict__ offs,
                                             const int* __restrict__ csr,
                                             const float* __restrict__ eemb,
                                             unsigned short* __restrict__ aggb) {
    __shared__ float semb[8 * 128];
    int tid = threadIdx.x;
    for (int i = tid; i < 1024; i += 256) semb[i] = eemb[i];
    __syncthreads();
    int node = blockIdx.x * 4 + (tid >> 6);
    int lane = tid & 63;
    int li = lane & 15, qd = lane >> 4;   // quarter-wave id
    int o0 = offs[node], o1 = offs[node + 1];
    int deg = o1 - o0;
    int degc = deg < 64 ? deg : 64;
    int ed = (lane < degc) ? csr[o0 + lane] : 0;   // coalesced: lane j = csr[o0+j]
    float a0 = 0.f, a1 = 0.f, a2 = 0.f, a3 = 0.f;
    float a4 = 0.f, a5 = 0.f, a6 = 0.f, a7 = 0.f;
    int nq0 = (degc + 3) >> 2;                     // wave-uniform bound (qd=0 count, max)
    int nql = degc > qd ? ((degc - qd + 3) >> 2) : 0;   // this quarter's valid count
    for (int j = 0; j < nq0; j += 16) {            // 16-deep batch per quarter
        int pk[16]; uint4 u[16];
        #pragma unroll
        for (int t = 0; t < 16; t++) {
            int sl = qd + 4 * (j + t);
            pk[t] = __shfl(ed, sl < 64 ? sl : 0);  // full wave active at every shfl
        }
        #pragma unroll
        for (int t = 0; t < 16; t++)
            u[t] = *(const uint4*)(xb + (size_t)(pk[t] & 0xFFFF) * 128 + li * 8);
        #pragma unroll
        for (int t = 0; t < 16; t++) {
            if (j + t < nql) {                     // predicate ADDS only (loads mem-safe)
                const float* ep = &semb[(pk[t] >> 16) * 128 + li * 8];
                float4 e0 = *(const float4*)ep;
                float4 e1 = *(const float4*)(ep + 4);
                a0 += fmaxf(blo(u[t].x) + e0.x, 0.f);
                a1 += fmaxf(bhi(u[t].x) + e0.y, 0.f);
                a2 += fmaxf(blo(u[t].y) + e0.z, 0.f);
                a3 += fmaxf(bhi(u[t].y) + e0.w, 0.f);
                a4 += fmaxf(blo(u[t].z) + e1.x, 0.f);
                a5 += fmaxf(bhi(u[t].z) + e1.y, 0.f);
                a6 += fmaxf(blo(u[t].w) + e1.z, 0.f);
                a7 += fmaxf(bhi(u[t].w) + e1.w, 0.f);
            }
        }
    }
    for (int i = 64 + qd; i < deg; i += 4) {       // deg>64 tail (absent here), no shfl
        int pk = csr[o0 + i];
        uint4 u = *(const uint4*)(xb + (size_t)(pk & 0xFFFF) * 128 + li * 8);
        const float* ep = &semb[(pk >> 16) * 128 + li * 8];
        float4 e0 = *(const float4*)ep;
        float4 e1 = *(const float4*)(ep + 4);
        a0 += fmaxf(blo(u.x) + e0.x, 0.f);
        a1 += fmaxf(bhi(u.x) + e0.y, 0.f);
        a2 += fmaxf(blo(u.y) + e0.z, 0.f);
        a3 += fmaxf(bhi(u.y) + e0.w, 0.f);
        a4 += fmaxf(blo(u.z) + e1.x, 0.f);
        a5 += fmaxf(bhi(u.z) + e1.y, 0.f);
        a6 += fmaxf(blo(u.w) + e1.z, 0.f);
        a7 += fmaxf(bhi(u.w) + e1.w, 0.f);
    }
    #pragma unroll
    for (int m = 16; m < 64; m <<= 1) {            // (q0+q1)+(q2+q3), all lanes active
        a0 += __shfl_xor(a0, m); a1 += __shfl_xor(a1, m);
        a2 += __shfl_xor(a2, m); a3 += __shfl_xor(a3, m);
        a4 += __shfl_xor(a4, m); a5 += __shfl_xor(a5, m);
        a6 += __shfl_xor(a6, m); a7 += __shfl_xor(a7, m);
    }
    if (qd == 0) {
        uint4 wv;
        wv.x = (unsigned int)f2b(a0) | ((unsigned int)f2b(a1) << 16);
        wv.y = (unsigned int)f2b(a2) | ((unsigned int)f2b(a3) << 16);
        wv.z = (unsigned int)f2b(a4) | ((unsigned int)f2b(a5) << 16);
        wv.w = (unsigned int)f2b(a6) | ((unsigned int)f2b(a7) << 16);
        *(uint4*)(aggb + (size_t)node * 128 + li * 8) = wv;
    }
}

// ---------------- fused GNN layer: x += LN(relu(agg@W1+b1)@W2+b2) ----------------
__global__ __launch_bounds__(512) void k_layer(const unsigned short* __restrict__ A,
                                               const unsigned short* __restrict__ W1T,
                                               const float* __restrict__ b1,
                                               const unsigned short* __restrict__ W2T,
                                               const float* __restrict__ b2,
                                               const float* __restrict__ lng,
                                               const float* __restrict__ lnb,
                                               float* __restrict__ x,
                                               unsigned short* __restrict__ xb) {
    __shared__ __align__(16) unsigned short WS[33792];     // 67.6 KB
    __shared__ __align__(16) unsigned short T[128][264];   // 67.6 KB
    int tid = threadIdx.x;
    int row0 = blockIdx.x * 128;
    int l = tid & 63, w = tid >> 6;
    int fr = l & 15, hi = l >> 4, fk = hi * 8;
    sh8 afr[4];
    #pragma unroll
    for (int kc = 0; kc < 4; kc++)
        afr[kc] = *(const sh8*)(A + (size_t)(row0 + w * 16 + fr) * 128 + kc * 32 + fk);
    #pragma unroll
    for (int s = tid; s < 4096; s += 512) {
        int n = s >> 4, k8 = s & 15;
        *(uint4*)&WS[n * 132 + k8 * 8] = *(const uint4*)(W1T + (size_t)n * 128 + k8 * 8);
    }
    __syncthreads();
    // ---- phase 1: T = relu(A @ W1 + b1), N=256 in 2 halves ----
    #pragma unroll
    for (int ch = 0; ch < 2; ch++) {
        f32x4 acc[8];
        #pragma unroll
        for (int c = 0; c < 8; c++) acc[c] = (f32x4){0.f, 0.f, 0.f, 0.f};
        #pragma unroll
        for (int kc = 0; kc < 4; kc++) {
            #pragma unroll
            for (int c = 0; c < 8; c++) {
                sh8 b = *(const sh8*)&WS[(ch * 128 + c * 16 + fr) * 132 + kc * 32 + fk];
                acc[c] = __builtin_amdgcn_mfma_f32_16x16x32_bf16(afr[kc], b, acc[c], 0, 0, 0);
            }
        }
        int rb = w * 16 + hi * 4;
        #pragma unroll
        for (int c = 0; c < 8; c++) {
            int col = ch * 128 + c * 16 + fr;
            float bv = b1[col];
            #pragma unroll
            for (int q = 0; q < 4; q++)
                T[rb + q][col] = f2b(fmaxf(acc[c][q] + bv, 0.f));
        }
    }
    __syncthreads();
    #pragma unroll
    for (int s = tid; s < 4096; s += 512) {
        int n = s >> 5, k8 = s & 31;
        *(uint4*)&WS[n * 264 + k8 * 8] = *(const uint4*)(W2T + (size_t)n * 256 + k8 * 8);
    }
    __syncthreads();
    // ---- phase 2: H = T @ W2 + b2 (K=256, N=128), LN, x += LN ----
    f32x4 acc[8];
    #pragma unroll
    for (int c = 0; c < 8; c++) acc[c] = (f32x4){0.f, 0.f, 0.f, 0.f};
    #pragma unroll 2
    for (int kc = 0; kc < 8; kc++) {
        sh8 a = *(const sh8*)&T[w * 16 + fr][kc * 32 + fk];
        #pragma unroll
        for (int c = 0; c < 8; c++) {
            sh8 b = *(const sh8*)&WS[(c * 16 + fr) * 264 + kc * 32 + fk];
            acc[c] = __builtin_amdgcn_mfma_f32_16x16x32_bf16(a, b, acc[c], 0, 0, 0);
        }
    }
    float s0 = 0.f, s1 = 0.f, s2 = 0.f, s3 = 0.f;
    float q0 = 0.f, q1 = 0.f, q2 = 0.f, q3 = 0.f;
    #pragma unroll
    for (int c = 0; c < 8; c++) {
        float bv = b2[c * 16 + fr];
        #pragma unroll
        for (int q = 0; q < 4; q++) acc[c][q] += bv;
        s0 += acc[c][0]; q0 += acc[c][0] * acc[c][0];
        s1 += acc[c][1]; q1 += acc[c][1] * acc[c][1];
        s2 += acc[c][2]; q2 += acc[c][2] * acc[c][2];
        s3 += acc[c][3]; q3 += acc[c][3] * acc[c][3];
    }
    #pragma unroll
    for (int m = 1; m < 16; m <<= 1) {
        s0 += __shfl_xor(s0, m); q0 += __shfl_xor(q0, m);
        s1 += __shfl_xor(s1, m); q1 += __shfl_xor(q1, m);
        s2 += __shfl_xor(s2, m); q2 += __shfl_xor(q2, m);
        s3 += __shfl_xor(s3, m); q3 += __shfl_xor(q3, m);
    }
    float mu[4], rs_[4];
    mu[0] = s0 * (1.f / 128.f); rs_[0] = rsqrtf(q0 * (1.f / 128.f) - mu[0] * mu[0] + 1e-5f);
    mu[1] = s1 * (1.f / 128.f); rs_[1] = rsqrtf(q1 * (1.f / 128.f) - mu[1] * mu[1] + 1e-5f);
    mu[2] = s2 * (1.f / 128.f); rs_[2] = rsqrtf(q2 * (1.f / 128.f) - mu[2] * mu[2] + 1e-5f);
    mu[3] = s3 * (1.f / 128.f); rs_[3] = rsqrtf(q3 * (1.f / 128.f) - mu[3] * mu[3] + 1e-5f);
    int rbase = row0 + w * 16 + hi * 4;
    #pragma unroll
    for (int c = 0; c < 8; c++) {
        int col = c * 16 + fr;
        float g = lng[col], bb = lnb[col];
        #pragma unroll
        for (int q = 0; q < 4; q++) {
            size_t idx = (size_t)(rbase + q) * 128 + col;
            float nx = x[idx] + (acc[c][q] - mu[q]) * rs_[q] * g + bb;
            x[idx] = nx;
            xb[idx] = f2b(nx);
        }
    }
}

// ---------------- fused gate (T-free) + softmax + attention pooling ----------------
__global__ __launch_bounds__(512) void k_gatepool(const unsigned short* __restrict__ xbin,
                                                  const float* __restrict__ xf,
                                                  const unsigned short* __restrict__ gW1T,
                                                  const float* __restrict__ b1,
                                                  const float* __restrict__ lng,
                                                  const float* __restrict__ lnb,
                                                  const float* __restrict__ w2,
                                                  const float* __restrict__ b2,
                                                  float* __restrict__ gpool) {
    __shared__ __align__(16) unsigned short WS[33792];
    __shared__ float gates[128];
    __shared__ float pooled[2][128];
    int tid = threadIdx.x;
    int row0 = blockIdx.x * 128;
    int l = tid & 63, w = tid >> 6;
    int fr = l & 15, hi = l >> 4, fk = hi * 8;
    sh8 afr[4];
    #pragma unroll
    for (int kc = 0; kc < 4; kc++)
        afr[kc] = *(const sh8*)(xbin + (size_t)(row0 + w * 16 + fr) * 128 + kc * 32 + fk);
    #pragma unroll
    for (int s = tid; s < 4096; s += 512) {
        int n = s >> 4, k8 = s & 15;
        *(uint4*)&WS[n * 132 + k8 * 8] = *(const uint4*)(gW1T + (size_t)n * 128 + k8 * 8);
    }
    __syncthreads();
    f32x4 acc[2][8];
    #pragma unroll
    for (int ch = 0; ch < 2; ch++)
        #pragma unroll
        for (int c = 0; c < 8; c++) acc[ch][c] = (f32x4){0.f, 0.f, 0.f, 0.f};
    #pragma unroll
    for (int kc = 0; kc < 4; kc++) {
        #pragma unroll
        for (int ch = 0; ch < 2; ch++) {
            #pragma unroll
            for (int c = 0; c < 8; c++) {
                sh8 b = *(const sh8*)&WS[(ch * 128 + c * 16 + fr) * 132 + kc * 32 + fk];
                acc[ch][c] = __builtin_amdgcn_mfma_f32_16x16x32_bf16(afr[kc], b, acc[ch][c], 0, 0, 0);
            }
        }
    }
    // epilogue: bias; LN stats over 256 cols (16 cols/lane x 16 fr-lanes); relu; dot w2
    float s[4] = {0.f, 0.f, 0.f, 0.f}, q[4] = {0.f, 0.f, 0.f, 0.f};
    #pragma unroll
    for (int ch = 0; ch < 2; ch++) {
        #pragma unroll
        for (int c = 0; c < 8; c++) {
            float bv = b1[ch * 128 + c * 16 + fr];
            #pragma unroll
            for (int qd = 0; qd < 4; qd++) {
                float v = acc[ch][c][qd] + bv;
                acc[ch][c][qd] = v;
                s[qd] += v; q[qd] += v * v;
            }
        }
    }
    #pragma unroll
    for (int m = 1; m < 16; m <<= 1) {
        #pragma unroll
        for (int qd = 0; qd < 4; qd++) {
            s[qd] += __shfl_xor(s[qd], m);
            q[qd] += __shfl_xor(q[qd], m);
        }
    }
    float mu[4], rcp[4];
    #pragma unroll
    for (int qd = 0; qd < 4; qd++) {
        mu[qd] = s[qd] * (1.f / 256.f);
        rcp[qd] = rsqrtf(q[qd] * (1.f / 256.f) - mu[qd] * mu[qd] + 1e-5f);
    }
    float dot[4] = {0.f, 0.f, 0.f, 0.f};
    #pragma unroll
    for (int ch = 0; ch < 2; ch++) {
        #pragma unroll
        for (int c = 0; c < 8; c++) {
            int col = ch * 128 + c * 16 + fr;
            float g = lng[col], bb = lnb[col], ww = w2[col];
            #pragma unroll
            for (int qd = 0; qd < 4; qd++) {
                float z = (acc[ch][c][qd] - mu[qd]) * rcp[qd] * g + bb;
                dot[qd] += fmaxf(z, 0.f) * ww;
            }
        }
    }
    #pragma unroll
    for (int m = 1; m < 16; m <<= 1)
        #pragma unroll
        for (int qd = 0; qd < 4; qd++) dot[qd] += __shfl_xor(dot[qd], m);
    if (fr == 0) {
        float b2v = b2[0];
        #pragma unroll
        for (int qd = 0; qd < 4; qd++)
            gates[w * 16 + hi * 4 + qd] = dot[qd] + b2v;
    }
    __syncthreads();
    // ---- phase B: softmax + pooling; graph group g = tid>>8 ----
    int g = tid >> 8, t2 = tid & 255;
    if (t2 < 64) {   // one full wave per graph (tid 0-63 / 256-319)
        float gv = gates[g * 64 + t2];
        float m = gv;
        #pragma unroll
        for (int mk = 1; mk < 64; mk <<= 1) m = fmaxf(m, __shfl_xor(m, mk));
        float e = expf(gv - m);
        float ss = e;
        #pragma unroll
        for (int mk = 1; mk < 64; mk <<= 1) ss += __shfl_xor(ss, mk);
        gates[g * 64 + t2] = e / ss;
    }
    __syncthreads();
    int d = t2 & 127, hh = t2 >> 7;
    float pacc = 0.f;
    for (int i = hh * 32; i < hh * 32 + 32; i++)
        pacc += gates[g * 64 + i] * xf[(size_t)(row0 + g * 64 + i) * 128 + d];
    if (hh == 0) pooled[g][d] = pacc;
    __syncthreads();
    if (hh == 1) gpool[(size_t)(blockIdx.x * 2 + g) * 128 + d] = pooled[g][d] + pacc;
}

// ---------------- residual blocks + head, one block per graph (fp32) ----------------
__global__ __launch_bounds__(128) void k_tail(const float* __restrict__ g_in,
        const float* __restrict__ fc1W, const float* __restrict__ fc1b,
        const float* __restrict__ ln1g, const float* __restrict__ ln1b,
        const float* __restrict__ fc2W, const float* __restrict__ fc2b,
        const float* __restrict__ ln2g, const float* __restrict__ ln2b,
        const float* __restrict__ pW1, const float* __restrict__ pb1,
        const float* __restrict__ pW2, const float* __restrict__ pb2,
        float* __restrict__ out) {
    __shared__ float sg[128], sh[128];
    __shared__ float ps[2], pq[2];
    int b = blockIdx.x, tid = threadIdx.x;
    int w = tid >> 6;
    sg[tid] = g_in[b * 128 + tid];
    __syncthreads();
    for (int r = 0; r < 2; r++) {
        const float* W1 = fc1W + r * 16384;
        float acc = fc1b[r * 128 + tid];
        for (int k = 0; k < 128; k++) acc += sg[k] * W1[k * 128 + tid];
        float s = acc, q = acc * acc;
        #pragma unroll
        for (int m = 1; m < 64; m <<= 1) { s += __shfl_xor(s, m); q += __shfl_xor(q, m); }
        __syncthreads();
        if ((tid & 63) == 0) { ps[w] = s; pq[w] = q; }
        __syncthreads();
        float S = ps[0] + ps[1], Q = pq[0] + pq[1];
        float mu = S * (1.f / 128.f);
        float var = Q * (1.f / 128.f) - mu * mu;
        float z = (acc - mu) * rsqrtf(var + 1e-5f) * ln1g[r * 128 + tid] + ln1b[r * 128 + tid];
        z = gelu_exact(z);
        __syncthreads();
        sh[tid] = z;
        __syncthreads();
        const float* W2 = fc2W + r * 16384;
        float acc2 = fc2b[r * 128 + tid];
        for (int k = 0; k < 128; k++) acc2 += sh[k] * W2[k * 128 + tid];
        s = acc2; q = acc2 * acc2;
        #pragma unroll
        for (int m = 1; m < 64; m <<= 1) { s += __shfl_xor(s, m); q += __shfl_xor(q, m); }
        __syncthreads();
        if ((tid & 63) == 0) { ps[w] = s; pq[w] = q; }
        __syncthreads();
        S = ps[0] + ps[1]; Q = pq[0] + pq[1];
        mu = S * (1.f / 128.f);
        var = Q * (1.f / 128.f) - mu * mu;
        float z2 = (acc2 - mu) * rsqrtf(var + 1e-5f) * ln2g[r * 128 + tid] + ln2b[r * 128 + tid];
        __syncthreads();
        sg[tid] = sg[tid] + z2;
        __syncthreads();
    }
    float acc = pb1[tid];
    for (int k = 0; k < 128; k++) acc += sg[k] * pW1[k * 128 + tid];
    __syncthreads();
    sh[tid] = gelu_exact(acc);
    __syncthreads();
    if (tid < 12) {
        float o = pb2[tid];
        for (int k = 0; k < 128; k++) o += sh[k] * pW2[k * 12 + tid];
        out[b * 12 + tid] = o;
    }
}

// ---------------- launch ----------------
extern "C" void kernel_launch(void* const* d_in, const int* in_sizes, int n_in,
                              void* d_out, int out_size, void* d_ws, size_t ws_size,
                              hipStream_t stream) {
    const float* logits    = (const float*)d_in[0];
    const int*   atom_feat = (const int*)d_in[2];
    const int*   edge_src  = (const int*)d_in[3];
    const int*   edge_dst  = edge_src + N_EDGES;
    const int*   edge_attr = (const int*)d_in[4];
    const float* atom_emb  = (const float*)d_in[6];
    const float* edge_emb  = (const float*)d_in[7];
    const float* gnn_W1    = (const float*)d_in[8];
    const float* gnn_b1    = (const float*)d_in[9];
    const float* gnn_W2    = (const float*)d_in[10];
    const float* gnn_b2    = (const float*)d_in[11];
    const float* gnn_ln_g  = (const float*)d_in[12];
    const float* gnn_ln_b  = (const float*)d_in[13];
    const float* gate_W1   = (const float*)d_in[14];
    const float* gate_b1   = (const float*)d_in[15];
    const float* gate_ln_g = (const float*)d_in[16];
    const float* gate_ln_b = (const float*)d_in[17];
    const float* gate_W2   = (const float*)d_in[18];
    const float* gate_b2   = (const float*)d_in[19];
    const float* res_fc1_W = (const float*)d_in[20];
    const float* res_fc1_b = (const float*)d_in[21];
    const float* res_ln1_g = (const float*)d_in[22];
    const float* res_ln1_b = (const float*)d_in[23];
    const float* res_fc2_W = (const float*)d_in[24];
    const float* res_fc2_b = (const float*)d_in[25];
    const float* res_ln2_g = (const float*)d_in[26];
    const float* res_ln2_b = (const float*)d_in[27];
    const float* pred_W1   = (const float*)d_in[28];
    const float* pred_b1   = (const float*)d_in[29];
    const float* pred_W2   = (const float*)d_in[30];
    const float* pred_b2   = (const float*)d_in[31];
    float* out = (float*)d_out;

    char* w = (char*)d_ws;
    float*          x    = (float*)w;          w += (size_t)N_NODES * 128 * 4;  // 16 MB fp32 master
    unsigned short* xb   = (unsigned short*)w; w += (size_t)N_NODES * 128 * 2;  // 8 MB bf16 shadow
    unsigned short* aggb = (unsigned short*)w; w += (size_t)N_NODES * 128 * 2;  // 8 MB
    unsigned short* W1T  = (unsigned short*)w; w += 3 * 32768 * 2;
    unsigned short* W2T  = (unsigned short*)w; w += 3 * 32768 * 2;
    unsigned short* gW1T = (unsigned short*)w; w += 32768 * 2;
    int*   deg    = (int*)w;   w += N_NODES * 4;
    int*   offs   = (int*)w;   w += (N_NODES + 64) * 4;
    int*   cursor = (int*)w;   w += N_NODES * 4;
    int*   csr    = (int*)w;   w += N_EDGES * 4;
    float* gpool  = (float*)w; w += B_GRAPHS * 128 * 4;

    // fused prep (weights + deg zero + build_x), then CSR build
    k_prep<<<PREP_BLOCKS + BX_BLOCKS, 256, 0, stream>>>(
        gnn_W1, gnn_W2, gate_W1, logits, atom_feat, atom_emb,
        W1T, W2T, gW1T, deg, x, xb);
    k_deg<<<N_EDGES / 256, 256, 0, stream>>>(edge_dst, deg);
    k_scan<<<1, 1024, 0, stream>>>(deg, offs, cursor);
    k_scatter<<<N_EDGES / 256, 256, 0, stream>>>(edge_src, edge_dst, edge_attr, cursor, csr);

    // 3 GNN layers: quarter-wave aggregation + fused MLP+LN+residual
    for (int l = 0; l < 3; l++) {
        k_agg<<<N_NODES / 4, 256, 0, stream>>>(xb, offs, csr, edge_emb, aggb);
        k_layer<<<N_NODES / 128, 512, 0, stream>>>(
            aggb, W1T + l * 32768, gnn_b1 + l * 256,
            W2T + l * 32768, gnn_b2 + l * 128,
            gnn_ln_g + l * 128, gnn_ln_b + l * 128, x, xb);
    }

    // fused gate + softmax + pooling, then tail
    k_gatepool<<<N_NODES / 128, 512, 0, stream>>>(
        xb, x, gW1T, gate_b1, gate_ln_g, gate_ln_b, gate_W2, gate_b2, gpool);
    k_tail<<<B_GRAPHS, 128, 0, stream>>>(gpool,
        res_fc1_W, res_fc1_b, res_ln1_g, res_ln1_b,
        res_fc2_W, res_fc2_b, res_ln2_g, res_ln2_b,
        pred_W1, pred_b1, pred_W2, pred_b2, out);
}

// Round 12
// 255.047 us; speedup vs baseline: 1.1672x; 1.1672x over previous
//
#include <hip/hip_runtime.h>
#include <hip/hip_bf16.h>

#define N_NODES 32768
#define N_EDGES 524288
#define B_GRAPHS 512

typedef __attribute__((ext_vector_type(8))) short sh8;    // 8 bf16 (4 VGPR) MFMA operand
typedef __attribute__((ext_vector_type(4))) float f32x4;  // MFMA accumulator

// ---------------- bf16 helpers ----------------
__device__ __forceinline__ unsigned short f2b(float f) {
    unsigned int u = __float_as_uint(f);
    return (unsigned short)((u + 0x7FFFu + ((u >> 16) & 1u)) >> 16);
}
__device__ __forceinline__ float blo(unsigned int u) { return __uint_as_float(u << 16); }
__device__ __forceinline__ float bhi(unsigned int u) { return __uint_as_float(u & 0xFFFF0000u); }
__device__ __forceinline__ float gelu_exact(float z) {
    return 0.5f * z * (1.0f + erff(z * 0.70710678118654752440f));
}

#define PREP_BLOCKS 896   // 7*32768/256
#define BX_BLOCKS 4096    // N_NODES*32/256

// ---------------- fused prep: weight transpose/bf16 + deg zero + build_x ----------------
__global__ __launch_bounds__(256) void k_prep(const float* __restrict__ W1,
                                              const float* __restrict__ W2,
                                              const float* __restrict__ gW1,
                                              const float* __restrict__ logits,
                                              const int* __restrict__ feat,
                                              const float* __restrict__ aemb,
                                              unsigned short* __restrict__ W1T,
                                              unsigned short* __restrict__ W2T,
                                              unsigned short* __restrict__ gW1T,
                                              int* __restrict__ deg,
                                              float* __restrict__ x,
                                              unsigned short* __restrict__ xb) {
    int bb = blockIdx.x;
    if (bb < PREP_BLOCKS) {
        int tid = bb * 256 + threadIdx.x;   // 7*32768 total
        if (tid < N_NODES) deg[tid] = 0;    // k_deg runs after on same stream
        int m = tid >> 15, i = tid & 32767;
        if (m < 3) {
            int r = i >> 8, c = i & 255;
            W1T[m * 32768 + c * 128 + r] = f2b(W1[m * 32768 + i]);   // [n=256][k=128]
        } else if (m < 6) {
            int mm = m - 3;
            int r = i >> 7, c = i & 127;
            W2T[mm * 32768 + c * 256 + r] = f2b(W2[mm * 32768 + i]); // [n=128][k=256]
        } else {
            int r = i >> 8, c = i & 255;
            gW1T[c * 128 + r] = f2b(gW1[i]);                         // [n=256][k=128]
        }
    } else {
        // build_x: x = logits[mask] + atom_emb[feat]  (fp32 master + bf16 shadow)
        int idx = (bb - PREP_BLOCKS) * 256 + threadIdx.x;   // float4 id, N_NODES*32 total
        int n = idx >> 5, c = idx & 31;
        int srow = ((n >> 6) << 7) + (n & 63);              // analytic nonzero(mask) index
        float4 lv = ((const float4*)logits)[srow * 32 + c];
        float4 av = ((const float4*)aemb)[feat[n] * 32 + c];
        float4 o;
        o.x = lv.x + av.x; o.y = lv.y + av.y; o.z = lv.z + av.z; o.w = lv.w + av.w;
        ((float4*)x)[idx] = o;
        ushort4 ob;
        ob.x = f2b(o.x); ob.y = f2b(o.y); ob.z = f2b(o.z); ob.w = f2b(o.w);
        ((ushort4*)xb)[idx] = ob;
    }
}

// ---------------- CSR build ----------------
__global__ void k_deg(const int* __restrict__ dst, int* __restrict__ deg) {
    int e = blockIdx.x * blockDim.x + threadIdx.x;
    if (e < N_EDGES) atomicAdd(&deg[dst[e]], 1);
}

__global__ __launch_bounds__(1024) void k_scan(const int* __restrict__ deg,
                                               int* __restrict__ offs,
                                               int* __restrict__ cursor) {
    int tid = threadIdx.x;
    int lane = tid & 63, wid = tid >> 6;
    int base = tid * 32;
    int pref[32];
    int run = 0;
    #pragma unroll
    for (int i = 0; i < 32; i++) { pref[i] = run; run += deg[base + i]; }
    int s = run;
    for (int m = 1; m < 64; m <<= 1) { int t = __shfl_up(s, m); if (lane >= m) s += t; }
    __shared__ int wsum[16];
    if (lane == 63) wsum[wid] = s;
    __syncthreads();
    if (tid < 16) {
        int v = wsum[tid];
        for (int m = 1; m < 16; m <<= 1) { int t = __shfl_up(v, m, 16); if (tid >= m) v += t; }
        wsum[tid] = v;
    }
    __syncthreads();
    int wbase = wid ? wsum[wid - 1] : 0;
    int ebase = wbase + (s - run);
    #pragma unroll
    for (int i = 0; i < 32; i++) {
        int o = ebase + pref[i];
        offs[base + i] = o;
        cursor[base + i] = o;
    }
    if (tid == 1023) offs[N_NODES] = ebase + run;
}

__global__ void k_scatter(const int* __restrict__ src, const int* __restrict__ dst,
                          const int* __restrict__ attr, int* __restrict__ cursor,
                          int* __restrict__ csr) {
    int e = blockIdx.x * blockDim.x + threadIdx.x;
    if (e < N_EDGES) {
        int p = atomicAdd(&cursor[dst[e]], 1);
        csr[p] = src[e] | (attr[e] << 16);
    }
}

// ---------------- per-node aggregation: FULL-WIDTH single pass (round-10 validated) ----------------
// Half-wave uint2 (32 lanes x 8B = one 512B VMEM instruction covers 2 edges), 8-deep
// batches, wave-uniform shfl broadcast (clamped source lane, adds predicated — shfl
// reads garbage from exec-inactive source lanes). Round-11's quarter-wave uint4/16-deep
// variant REGRESSED (+43us): 1M LDS bank conflicts (stride-8-float semb reads) and the
// allocator refused ~80 in-flight regs (VGPR_Count=60 -> loads serialized). This shape
// is the measured optimum of the family. aggb bit-identical to round 6/8/10.
__global__ __launch_bounds__(256) void k_agg(const unsigned short* __restrict__ xb,
                                             const int* __restrict__ offs,
                                             const int* __restrict__ csr,
                                             const float* __restrict__ eemb,
                                             unsigned short* __restrict__ aggb) {
    __shared__ float semb[8 * 128];
    int tid = threadIdx.x;
    for (int i = tid; i < 1024; i += 256) semb[i] = eemb[i];
    __syncthreads();
    int node = blockIdx.x * 4 + (tid >> 6);
    int lane = tid & 63;
    int li = lane & 31, h = lane >> 5;   // half-wave: h=0 even edges, h=1 odd edges
    int o0 = offs[node], o1 = offs[node + 1];
    int deg = o1 - o0;
    int degc = deg < 64 ? deg : 64;
    int ed = (lane < degc) ? csr[o0 + lane] : 0;   // coalesced: lane j = csr[o0+j]
    float a0 = 0.f, a1 = 0.f, a2 = 0.f, a3 = 0.f;
    int nh0 = (degc + 1) >> 1;           // wave-uniform loop bound
    int nhl = h ? (degc >> 1) : nh0;     // this lane's valid-edge count
    for (int j = 0; j < nh0; j += 8) {   // uniform batches; lanes clamped, adds predicated
        int pk[8]; uint2 u[8];
        #pragma unroll
        for (int t = 0; t < 8; t++) {
            int sl = h + 2 * (j + t);
            pk[t] = __shfl(ed, sl < 64 ? sl : 0);   // full wave active at every shfl
        }
        #pragma unroll
        for (int t = 0; t < 8; t++)
            u[t] = *(const uint2*)(xb + (size_t)(pk[t] & 0xFFFF) * 128 + li * 4);
        #pragma unroll
        for (int t = 0; t < 8; t++) {
            if (j + t < nhl) {           // predicate ADDS only (loads are memory-safe)
                float4 ev = *(const float4*)&semb[(pk[t] >> 16) * 128 + li * 4];
                a0 += fmaxf(blo(u[t].x) + ev.x, 0.f);
                a1 += fmaxf(bhi(u[t].x) + ev.y, 0.f);
                a2 += fmaxf(blo(u[t].y) + ev.z, 0.f);
                a3 += fmaxf(bhi(u[t].y) + ev.w, 0.f);
            }
        }
    }
    for (int i = 64 + h; i < deg; i += 2) {   // deg>64 tail (absent for this data), no shfl
        int pk = csr[o0 + i];
        uint2 u = *(const uint2*)(xb + (size_t)(pk & 0xFFFF) * 128 + li * 4);
        float4 ev = *(const float4*)&semb[(pk >> 16) * 128 + li * 4];
        a0 += fmaxf(blo(u.x) + ev.x, 0.f);
        a1 += fmaxf(bhi(u.x) + ev.y, 0.f);
        a2 += fmaxf(blo(u.y) + ev.z, 0.f);
        a3 += fmaxf(bhi(u.y) + ev.w, 0.f);
    }
    a0 += __shfl_xor(a0, 32); a1 += __shfl_xor(a1, 32);   // even-sum + odd-sum
    a2 += __shfl_xor(a2, 32); a3 += __shfl_xor(a3, 32);
    if (h == 0) {
        uint2 wv;
        wv.x = (unsigned int)f2b(a0) | ((unsigned int)f2b(a1) << 16);
        wv.y = (unsigned int)f2b(a2) | ((unsigned int)f2b(a3) << 16);
        *(uint2*)(aggb + (size_t)node * 128 + li * 4) = wv;
    }
}

// ---------------- fused GNN layer: x += LN(relu(agg@W1+b1)@W2+b2) ----------------
__global__ __launch_bounds__(512) void k_layer(const unsigned short* __restrict__ A,
                                               const unsigned short* __restrict__ W1T,
                                               const float* __restrict__ b1,
                                               const unsigned short* __restrict__ W2T,
                                               const float* __restrict__ b2,
                                               const float* __restrict__ lng,
                                               const float* __restrict__ lnb,
                                               float* __restrict__ x,
                                               unsigned short* __restrict__ xb) {
    __shared__ __align__(16) unsigned short WS[33792];     // 67.6 KB
    __shared__ __align__(16) unsigned short T[128][264];   // 67.6 KB
    int tid = threadIdx.x;
    int row0 = blockIdx.x * 128;
    int l = tid & 63, w = tid >> 6;
    int fr = l & 15, hi = l >> 4, fk = hi * 8;
    sh8 afr[4];
    #pragma unroll
    for (int kc = 0; kc < 4; kc++)
        afr[kc] = *(const sh8*)(A + (size_t)(row0 + w * 16 + fr) * 128 + kc * 32 + fk);
    #pragma unroll
    for (int s = tid; s < 4096; s += 512) {
        int n = s >> 4, k8 = s & 15;
        *(uint4*)&WS[n * 132 + k8 * 8] = *(const uint4*)(W1T + (size_t)n * 128 + k8 * 8);
    }
    __syncthreads();
    // ---- phase 1: T = relu(A @ W1 + b1), N=256 in 2 halves ----
    #pragma unroll
    for (int ch = 0; ch < 2; ch++) {
        f32x4 acc[8];
        #pragma unroll
        for (int c = 0; c < 8; c++) acc[c] = (f32x4){0.f, 0.f, 0.f, 0.f};
        #pragma unroll
        for (int kc = 0; kc < 4; kc++) {
            #pragma unroll
            for (int c = 0; c < 8; c++) {
                sh8 b = *(const sh8*)&WS[(ch * 128 + c * 16 + fr) * 132 + kc * 32 + fk];
                acc[c] = __builtin_amdgcn_mfma_f32_16x16x32_bf16(afr[kc], b, acc[c], 0, 0, 0);
            }
        }
        int rb = w * 16 + hi * 4;
        #pragma unroll
        for (int c = 0; c < 8; c++) {
            int col = ch * 128 + c * 16 + fr;
            float bv = b1[col];
            #pragma unroll
            for (int q = 0; q < 4; q++)
                T[rb + q][col] = f2b(fmaxf(acc[c][q] + bv, 0.f));
        }
    }
    __syncthreads();
    #pragma unroll
    for (int s = tid; s < 4096; s += 512) {
        int n = s >> 5, k8 = s & 31;
        *(uint4*)&WS[n * 264 + k8 * 8] = *(const uint4*)(W2T + (size_t)n * 256 + k8 * 8);
    }
    __syncthreads();
    // ---- phase 2: H = T @ W2 + b2 (K=256, N=128), LN, x += LN ----
    f32x4 acc[8];
    #pragma unroll
    for (int c = 0; c < 8; c++) acc[c] = (f32x4){0.f, 0.f, 0.f, 0.f};
    #pragma unroll 2
    for (int kc = 0; kc < 8; kc++) {
        sh8 a = *(const sh8*)&T[w * 16 + fr][kc * 32 + fk];
        #pragma unroll
        for (int c = 0; c < 8; c++) {
            sh8 b = *(const sh8*)&WS[(c * 16 + fr) * 264 + kc * 32 + fk];
            acc[c] = __builtin_amdgcn_mfma_f32_16x16x32_bf16(a, b, acc[c], 0, 0, 0);
        }
    }
    float s0 = 0.f, s1 = 0.f, s2 = 0.f, s3 = 0.f;
    float q0 = 0.f, q1 = 0.f, q2 = 0.f, q3 = 0.f;
    #pragma unroll
    for (int c = 0; c < 8; c++) {
        float bv = b2[c * 16 + fr];
        #pragma unroll
        for (int q = 0; q < 4; q++) acc[c][q] += bv;
        s0 += acc[c][0]; q0 += acc[c][0] * acc[c][0];
        s1 += acc[c][1]; q1 += acc[c][1] * acc[c][1];
        s2 += acc[c][2]; q2 += acc[c][2] * acc[c][2];
        s3 += acc[c][3]; q3 += acc[c][3] * acc[c][3];
    }
    #pragma unroll
    for (int m = 1; m < 16; m <<= 1) {
        s0 += __shfl_xor(s0, m); q0 += __shfl_xor(q0, m);
        s1 += __shfl_xor(s1, m); q1 += __shfl_xor(q1, m);
        s2 += __shfl_xor(s2, m); q2 += __shfl_xor(q2, m);
        s3 += __shfl_xor(s3, m); q3 += __shfl_xor(q3, m);
    }
    float mu[4], rs_[4];
    mu[0] = s0 * (1.f / 128.f); rs_[0] = rsqrtf(q0 * (1.f / 128.f) - mu[0] * mu[0] + 1e-5f);
    mu[1] = s1 * (1.f / 128.f); rs_[1] = rsqrtf(q1 * (1.f / 128.f) - mu[1] * mu[1] + 1e-5f);
    mu[2] = s2 * (1.f / 128.f); rs_[2] = rsqrtf(q2 * (1.f / 128.f) - mu[2] * mu[2] + 1e-5f);
    mu[3] = s3 * (1.f / 128.f); rs_[3] = rsqrtf(q3 * (1.f / 128.f) - mu[3] * mu[3] + 1e-5f);
    int rbase = row0 + w * 16 + hi * 4;
    #pragma unroll
    for (int c = 0; c < 8; c++) {
        int col = c * 16 + fr;
        float g = lng[col], bb = lnb[col];
        #pragma unroll
        for (int q = 0; q < 4; q++) {
            size_t idx = (size_t)(rbase + q) * 128 + col;
            float nx = x[idx] + (acc[c][q] - mu[q]) * rs_[q] * g + bb;
            x[idx] = nx;
            xb[idx] = f2b(nx);
        }
    }
}

// ---------------- fused gate (T-free) + softmax + attention pooling ----------------
__global__ __launch_bounds__(512) void k_gatepool(const unsigned short* __restrict__ xbin,
                                                  const float* __restrict__ xf,
                                                  const unsigned short* __restrict__ gW1T,
                                                  const float* __restrict__ b1,
                                                  const float* __restrict__ lng,
                                                  const float* __restrict__ lnb,
                                                  const float* __restrict__ w2,
                                                  const float* __restrict__ b2,
                                                  float* __restrict__ gpool) {
    __shared__ __align__(16) unsigned short WS[33792];
    __shared__ float gates[128];
    __shared__ float pooled[2][128];
    int tid = threadIdx.x;
    int row0 = blockIdx.x * 128;
    int l = tid & 63, w = tid >> 6;
    int fr = l & 15, hi = l >> 4, fk = hi * 8;
    sh8 afr[4];
    #pragma unroll
    for (int kc = 0; kc < 4; kc++)
        afr[kc] = *(const sh8*)(xbin + (size_t)(row0 + w * 16 + fr) * 128 + kc * 32 + fk);
    #pragma unroll
    for (int s = tid; s < 4096; s += 512) {
        int n = s >> 4, k8 = s & 15;
        *(uint4*)&WS[n * 132 + k8 * 8] = *(const uint4*)(gW1T + (size_t)n * 128 + k8 * 8);
    }
    __syncthreads();
    f32x4 acc[2][8];
    #pragma unroll
    for (int ch = 0; ch < 2; ch++)
        #pragma unroll
        for (int c = 0; c < 8; c++) acc[ch][c] = (f32x4){0.f, 0.f, 0.f, 0.f};
    #pragma unroll
    for (int kc = 0; kc < 4; kc++) {
        #pragma unroll
        for (int ch = 0; ch < 2; ch++) {
            #pragma unroll
            for (int c = 0; c < 8; c++) {
                sh8 b = *(const sh8*)&WS[(ch * 128 + c * 16 + fr) * 132 + kc * 32 + fk];
                acc[ch][c] = __builtin_amdgcn_mfma_f32_16x16x32_bf16(afr[kc], b, acc[ch][c], 0, 0, 0);
            }
        }
    }
    // epilogue: bias; LN stats over 256 cols (16 cols/lane x 16 fr-lanes); relu; dot w2
    float s[4] = {0.f, 0.f, 0.f, 0.f}, q[4] = {0.f, 0.f, 0.f, 0.f};
    #pragma unroll
    for (int ch = 0; ch < 2; ch++) {
        #pragma unroll
        for (int c = 0; c < 8; c++) {
            float bv = b1[ch * 128 + c * 16 + fr];
            #pragma unroll
            for (int qd = 0; qd < 4; qd++) {
                float v = acc[ch][c][qd] + bv;
                acc[ch][c][qd] = v;
                s[qd] += v; q[qd] += v * v;
            }
        }
    }
    #pragma unroll
    for (int m = 1; m < 16; m <<= 1) {
        #pragma unroll
        for (int qd = 0; qd < 4; qd++) {
            s[qd] += __shfl_xor(s[qd], m);
            q[qd] += __shfl_xor(q[qd], m);
        }
    }
    float mu[4], rcp[4];
    #pragma unroll
    for (int qd = 0; qd < 4; qd++) {
        mu[qd] = s[qd] * (1.f / 256.f);
        rcp[qd] = rsqrtf(q[qd] * (1.f / 256.f) - mu[qd] * mu[qd] + 1e-5f);
    }
    float dot[4] = {0.f, 0.f, 0.f, 0.f};
    #pragma unroll
    for (int ch = 0; ch < 2; ch++) {
        #pragma unroll
        for (int c = 0; c < 8; c++) {
            int col = ch * 128 + c * 16 + fr;
            float g = lng[col], bb = lnb[col], ww = w2[col];
            #pragma unroll
            for (int qd = 0; qd < 4; qd++) {
                float z = (acc[ch][c][qd] - mu[qd]) * rcp[qd] * g + bb;
                dot[qd] += fmaxf(z, 0.f) * ww;
            }
        }
    }
    #pragma unroll
    for (int m = 1; m < 16; m <<= 1)
        #pragma unroll
        for (int qd = 0; qd < 4; qd++) dot[qd] += __shfl_xor(dot[qd], m);
    if (fr == 0) {
        float b2v = b2[0];
        #pragma unroll
        for (int qd = 0; qd < 4; qd++)
            gates[w * 16 + hi * 4 + qd] = dot[qd] + b2v;
    }
    __syncthreads();
    // ---- phase B: softmax + pooling; graph group g = tid>>8 ----
    int g = tid >> 8, t2 = tid & 255;
    if (t2 < 64) {   // one full wave per graph (tid 0-63 / 256-319)
        float gv = gates[g * 64 + t2];
        float m = gv;
        #pragma unroll
        for (int mk = 1; mk < 64; mk <<= 1) m = fmaxf(m, __shfl_xor(m, mk));
        float e = expf(gv - m);
        float ss = e;
        #pragma unroll
        for (int mk = 1; mk < 64; mk <<= 1) ss += __shfl_xor(ss, mk);
        gates[g * 64 + t2] = e / ss;
    }
    __syncthreads();
    int d = t2 & 127, hh = t2 >> 7;
    float pacc = 0.f;
    for (int i = hh * 32; i < hh * 32 + 32; i++)
        pacc += gates[g * 64 + i] * xf[(size_t)(row0 + g * 64 + i) * 128 + d];
    if (hh == 0) pooled[g][d] = pacc;
    __syncthreads();
    if (hh == 1) gpool[(size_t)(blockIdx.x * 2 + g) * 128 + d] = pooled[g][d] + pacc;
}

// ---------------- residual blocks + head, one block per graph (fp32) ----------------
__global__ __launch_bounds__(128) void k_tail(const float* __restrict__ g_in,
        const float* __restrict__ fc1W, const float* __restrict__ fc1b,
        const float* __restrict__ ln1g, const float* __restrict__ ln1b,
        const float* __restrict__ fc2W, const float* __restrict__ fc2b,
        const float* __restrict__ ln2g, const float* __restrict__ ln2b,
        const float* __restrict__ pW1, const float* __restrict__ pb1,
        const float* __restrict__ pW2, const float* __restrict__ pb2,
        float* __restrict__ out) {
    __shared__ float sg[128], sh[128];
    __shared__ float ps[2], pq[2];
    int b = blockIdx.x, tid = threadIdx.x;
    int w = tid >> 6;
    sg[tid] = g_in[b * 128 + tid];
    __syncthreads();
    for (int r = 0; r < 2; r++) {
        const float* W1 = fc1W + r * 16384;
        float acc = fc1b[r * 128 + tid];
        for (int k = 0; k < 128; k++) acc += sg[k] * W1[k * 128 + tid];
        float s = acc, q = acc * acc;
        #pragma unroll
        for (int m = 1; m < 64; m <<= 1) { s += __shfl_xor(s, m); q += __shfl_xor(q, m); }
        __syncthreads();
        if ((tid & 63) == 0) { ps[w] = s; pq[w] = q; }
        __syncthreads();
        float S = ps[0] + ps[1], Q = pq[0] + pq[1];
        float mu = S * (1.f / 128.f);
        float var = Q * (1.f / 128.f) - mu * mu;
        float z = (acc - mu) * rsqrtf(var + 1e-5f) * ln1g[r * 128 + tid] + ln1b[r * 128 + tid];
        z = gelu_exact(z);
        __syncthreads();
        sh[tid] = z;
        __syncthreads();
        const float* W2 = fc2W + r * 16384;
        float acc2 = fc2b[r * 128 + tid];
        for (int k = 0; k < 128; k++) acc2 += sh[k] * W2[k * 128 + tid];
        s = acc2; q = acc2 * acc2;
        #pragma unroll
        for (int m = 1; m < 64; m <<= 1) { s += __shfl_xor(s, m); q += __shfl_xor(q, m); }
        __syncthreads();
        if ((tid & 63) == 0) { ps[w] = s; pq[w] = q; }
        __syncthreads();
        S = ps[0] + ps[1]; Q = pq[0] + pq[1];
        mu = S * (1.f / 128.f);
        var = Q * (1.f / 128.f) - mu * mu;
        float z2 = (acc2 - mu) * rsqrtf(var + 1e-5f) * ln2g[r * 128 + tid] + ln2b[r * 128 + tid];
        __syncthreads();
        sg[tid] = sg[tid] + z2;
        __syncthreads();
    }
    float acc = pb1[tid];
    for (int k = 0; k < 128; k++) acc += sg[k] * pW1[k * 128 + tid];
    __syncthreads();
    sh[tid] = gelu_exact(acc);
    __syncthreads();
    if (tid < 12) {
        float o = pb2[tid];
        for (int k = 0; k < 128; k++) o += sh[k] * pW2[k * 12 + tid];
        out[b * 12 + tid] = o;
    }
}

// ---------------- launch ----------------
extern "C" void kernel_launch(void* const* d_in, const int* in_sizes, int n_in,
                              void* d_out, int out_size, void* d_ws, size_t ws_size,
                              hipStream_t stream) {
    const float* logits    = (const float*)d_in[0];
    const int*   atom_feat = (const int*)d_in[2];
    const int*   edge_src  = (const int*)d_in[3];
    const int*   edge_dst  = edge_src + N_EDGES;
    const int*   edge_attr = (const int*)d_in[4];
    const float* atom_emb  = (const float*)d_in[6];
    const float* edge_emb  = (const float*)d_in[7];
    const float* gnn_W1    = (const float*)d_in[8];
    const float* gnn_b1    = (const float*)d_in[9];
    const float* gnn_W2    = (const float*)d_in[10];
    const float* gnn_b2    = (const float*)d_in[11];
    const float* gnn_ln_g  = (const float*)d_in[12];
    const float* gnn_ln_b  = (const float*)d_in[13];
    const float* gate_W1   = (const float*)d_in[14];
    const float* gate_b1   = (const float*)d_in[15];
    const float* gate_ln_g = (const float*)d_in[16];
    const float* gate_ln_b = (const float*)d_in[17];
    const float* gate_W2   = (const float*)d_in[18];
    const float* gate_b2   = (const float*)d_in[19];
    const float* res_fc1_W = (const float*)d_in[20];
    const float* res_fc1_b = (const float*)d_in[21];
    const float* res_ln1_g = (const float*)d_in[22];
    const float* res_ln1_b = (const float*)d_in[23];
    const float* res_fc2_W = (const float*)d_in[24];
    const float* res_fc2_b = (const float*)d_in[25];
    const float* res_ln2_g = (const float*)d_in[26];
    const float* res_ln2_b = (const float*)d_in[27];
    const float* pred_W1   = (const float*)d_in[28];
    const float* pred_b1   = (const float*)d_in[29];
    const float* pred_W2   = (const float*)d_in[30];
    const float* pred_b2   = (const float*)d_in[31];
    float* out = (float*)d_out;

    char* w = (char*)d_ws;
    float*          x    = (float*)w;          w += (size_t)N_NODES * 128 * 4;  // 16 MB fp32 master
    unsigned short* xb   = (unsigned short*)w; w += (size_t)N_NODES * 128 * 2;  // 8 MB bf16 shadow
    unsigned short* aggb = (unsigned short*)w; w += (size_t)N_NODES * 128 * 2;  // 8 MB
    unsigned short* W1T  = (unsigned short*)w; w += 3 * 32768 * 2;
    unsigned short* W2T  = (unsigned short*)w; w += 3 * 32768 * 2;
    unsigned short* gW1T = (unsigned short*)w; w += 32768 * 2;
    int*   deg    = (int*)w;   w += N_NODES * 4;
    int*   offs   = (int*)w;   w += (N_NODES + 64) * 4;
    int*   cursor = (int*)w;   w += N_NODES * 4;
    int*   csr    = (int*)w;   w += N_EDGES * 4;
    float* gpool  = (float*)w; w += B_GRAPHS * 128 * 4;

    // fused prep (weights + deg zero + build_x), then CSR build
    k_prep<<<PREP_BLOCKS + BX_BLOCKS, 256, 0, stream>>>(
        gnn_W1, gnn_W2, gate_W1, logits, atom_feat, atom_emb,
        W1T, W2T, gW1T, deg, x, xb);
    k_deg<<<N_EDGES / 256, 256, 0, stream>>>(edge_dst, deg);
    k_scan<<<1, 1024, 0, stream>>>(deg, offs, cursor);
    k_scatter<<<N_EDGES / 256, 256, 0, stream>>>(edge_src, edge_dst, edge_attr, cursor, csr);

    // 3 GNN layers: full-width aggregation + fused MLP+LN+residual
    for (int l = 0; l < 3; l++) {
        k_agg<<<N_NODES / 4, 256, 0, stream>>>(xb, offs, csr, edge_emb, aggb);
        k_layer<<<N_NODES / 128, 512, 0, stream>>>(
            aggb, W1T + l * 32768, gnn_b1 + l * 256,
            W2T + l * 32768, gnn_b2 + l * 128,
            gnn_ln_g + l * 128, gnn_ln_b + l * 128, x, xb);
    }

    // fused gate + softmax + pooling, then tail
    k_gatepool<<<N_NODES / 128, 512, 0, stream>>>(
        xb, x, gW1T, gate_b1, gate_ln_g, gate_ln_b, gate_W2, gate_b2, gpool);
    k_tail<<<B_GRAPHS, 128, 0, stream>>>(gpool,
        res_fc1_W, res_fc1_b, res_ln1_g, res_ln1_b,
        res_fc2_W, res_fc2_b, res_ln2_g, res_ln2_b,
        pred_W1, pred_b1, pred_W2, pred_b2, out);
}

// Round 13
// 253.089 us; speedup vs baseline: 1.1763x; 1.0077x over previous
//
#include <hip/hip_runtime.h>
#include <hip/hip_bf16.h>

#define N_NODES 32768
#define N_EDGES 524288
#define B_GRAPHS 512

typedef __attribute__((ext_vector_type(8))) short sh8;    // 8 bf16 (4 VGPR) MFMA operand
typedef __attribute__((ext_vector_type(4))) float f32x4;  // MFMA accumulator

// ---------------- bf16 helpers ----------------
__device__ __forceinline__ unsigned short f2b(float f) {
    unsigned int u = __float_as_uint(f);
    return (unsigned short)((u + 0x7FFFu + ((u >> 16) & 1u)) >> 16);
}
__device__ __forceinline__ float blo(unsigned int u) { return __uint_as_float(u << 16); }
__device__ __forceinline__ float bhi(unsigned int u) { return __uint_as_float(u & 0xFFFF0000u); }
__device__ __forceinline__ float gelu_exact(float z) {
    return 0.5f * z * (1.0f + erff(z * 0.70710678118654752440f));
}

#define PREP_BLOCKS 896   // 7*32768/256
#define BX_BLOCKS 4096    // N_NODES*32/256

// ---------------- fused prep: weight transpose/bf16 + deg zero + build_x ----------------
__global__ __launch_bounds__(256) void k_prep(const float* __restrict__ W1,
                                              const float* __restrict__ W2,
                                              const float* __restrict__ gW1,
                                              const float* __restrict__ logits,
                                              const int* __restrict__ feat,
                                              const float* __restrict__ aemb,
                                              unsigned short* __restrict__ W1T,
                                              unsigned short* __restrict__ W2T,
                                              unsigned short* __restrict__ gW1T,
                                              int* __restrict__ deg,
                                              float* __restrict__ x,
                                              unsigned short* __restrict__ xb) {
    int bb = blockIdx.x;
    if (bb < PREP_BLOCKS) {
        int tid = bb * 256 + threadIdx.x;   // 7*32768 total
        if (tid < N_NODES) deg[tid] = 0;    // k_deg runs after on same stream
        int m = tid >> 15, i = tid & 32767;
        if (m < 3) {
            int r = i >> 8, c = i & 255;
            W1T[m * 32768 + c * 128 + r] = f2b(W1[m * 32768 + i]);   // [n=256][k=128]
        } else if (m < 6) {
            int mm = m - 3;
            int r = i >> 7, c = i & 127;
            W2T[mm * 32768 + c * 256 + r] = f2b(W2[mm * 32768 + i]); // [n=128][k=256]
        } else {
            int r = i >> 8, c = i & 255;
            gW1T[c * 128 + r] = f2b(gW1[i]);                         // [n=256][k=128]
        }
    } else {
        // build_x: x = logits[mask] + atom_emb[feat]  (fp32 master + bf16 shadow)
        int idx = (bb - PREP_BLOCKS) * 256 + threadIdx.x;   // float4 id, N_NODES*32 total
        int n = idx >> 5, c = idx & 31;
        int srow = ((n >> 6) << 7) + (n & 63);              // analytic nonzero(mask) index
        float4 lv = ((const float4*)logits)[srow * 32 + c];
        float4 av = ((const float4*)aemb)[feat[n] * 32 + c];
        float4 o;
        o.x = lv.x + av.x; o.y = lv.y + av.y; o.z = lv.z + av.z; o.w = lv.w + av.w;
        ((float4*)x)[idx] = o;
        ushort4 ob;
        ob.x = f2b(o.x); ob.y = f2b(o.y); ob.z = f2b(o.z); ob.w = f2b(o.w);
        ((ushort4*)xb)[idx] = ob;
    }
}

// ---------------- CSR build ----------------
__global__ void k_deg(const int* __restrict__ dst, int* __restrict__ deg) {
    int e = blockIdx.x * blockDim.x + threadIdx.x;
    if (e < N_EDGES) atomicAdd(&deg[dst[e]], 1);
}

__global__ __launch_bounds__(1024) void k_scan(const int* __restrict__ deg,
                                               int* __restrict__ offs,
                                               int* __restrict__ cursor) {
    int tid = threadIdx.x;
    int lane = tid & 63, wid = tid >> 6;
    int base = tid * 32;
    int pref[32];
    int run = 0;
    #pragma unroll
    for (int i = 0; i < 32; i++) { pref[i] = run; run += deg[base + i]; }
    int s = run;
    for (int m = 1; m < 64; m <<= 1) { int t = __shfl_up(s, m); if (lane >= m) s += t; }
    __shared__ int wsum[16];
    if (lane == 63) wsum[wid] = s;
    __syncthreads();
    if (tid < 16) {
        int v = wsum[tid];
        for (int m = 1; m < 16; m <<= 1) { int t = __shfl_up(v, m, 16); if (tid >= m) v += t; }
        wsum[tid] = v;
    }
    __syncthreads();
    int wbase = wid ? wsum[wid - 1] : 0;
    int ebase = wbase + (s - run);
    #pragma unroll
    for (int i = 0; i < 32; i++) {
        int o = ebase + pref[i];
        offs[base + i] = o;
        cursor[base + i] = o;
    }
    if (tid == 1023) offs[N_NODES] = ebase + run;
}

__global__ void k_scatter(const int* __restrict__ src, const int* __restrict__ dst,
                          const int* __restrict__ attr, int* __restrict__ cursor,
                          int* __restrict__ csr) {
    int e = blockIdx.x * blockDim.x + threadIdx.x;
    if (e < N_EDGES) {
        int p = atomicAdd(&cursor[dst[e]], 1);
        csr[p] = src[e] | (attr[e] << 16);
    }
}

// ---------------- per-node aggregation: FULL-WIDTH single pass (round-10/12 validated) ----------------
// Half-wave uint2 (one 512B VMEM instruction covers 2 edges), 8-deep batches, wave-
// uniform shfl broadcast (clamped source lane, adds predicated). Family history:
// feature-slicing +20us (r9), quarter-wave uint4/16-deep +43us (r11: 1M LDS bank
// conflicts + allocator refused in-flight regs). This shape is the measured optimum.
__global__ __launch_bounds__(256) void k_agg(const unsigned short* __restrict__ xb,
                                             const int* __restrict__ offs,
                                             const int* __restrict__ csr,
                                             const float* __restrict__ eemb,
                                             unsigned short* __restrict__ aggb) {
    __shared__ float semb[8 * 128];
    int tid = threadIdx.x;
    for (int i = tid; i < 1024; i += 256) semb[i] = eemb[i];
    __syncthreads();
    int node = blockIdx.x * 4 + (tid >> 6);
    int lane = tid & 63;
    int li = lane & 31, h = lane >> 5;   // half-wave: h=0 even edges, h=1 odd edges
    int o0 = offs[node], o1 = offs[node + 1];
    int deg = o1 - o0;
    int degc = deg < 64 ? deg : 64;
    int ed = (lane < degc) ? csr[o0 + lane] : 0;   // coalesced: lane j = csr[o0+j]
    float a0 = 0.f, a1 = 0.f, a2 = 0.f, a3 = 0.f;
    int nh0 = (degc + 1) >> 1;           // wave-uniform loop bound
    int nhl = h ? (degc >> 1) : nh0;     // this lane's valid-edge count
    for (int j = 0; j < nh0; j += 8) {   // uniform batches; lanes clamped, adds predicated
        int pk[8]; uint2 u[8];
        #pragma unroll
        for (int t = 0; t < 8; t++) {
            int sl = h + 2 * (j + t);
            pk[t] = __shfl(ed, sl < 64 ? sl : 0);   // full wave active at every shfl
        }
        #pragma unroll
        for (int t = 0; t < 8; t++)
            u[t] = *(const uint2*)(xb + (size_t)(pk[t] & 0xFFFF) * 128 + li * 4);
        #pragma unroll
        for (int t = 0; t < 8; t++) {
            if (j + t < nhl) {           // predicate ADDS only (loads are memory-safe)
                float4 ev = *(const float4*)&semb[(pk[t] >> 16) * 128 + li * 4];
                a0 += fmaxf(blo(u[t].x) + ev.x, 0.f);
                a1 += fmaxf(bhi(u[t].x) + ev.y, 0.f);
                a2 += fmaxf(blo(u[t].y) + ev.z, 0.f);
                a3 += fmaxf(bhi(u[t].y) + ev.w, 0.f);
            }
        }
    }
    for (int i = 64 + h; i < deg; i += 2) {   // deg>64 tail (absent for this data), no shfl
        int pk = csr[o0 + i];
        uint2 u = *(const uint2*)(xb + (size_t)(pk & 0xFFFF) * 128 + li * 4);
        float4 ev = *(const float4*)&semb[(pk >> 16) * 128 + li * 4];
        a0 += fmaxf(blo(u.x) + ev.x, 0.f);
        a1 += fmaxf(bhi(u.x) + ev.y, 0.f);
        a2 += fmaxf(blo(u.y) + ev.z, 0.f);
        a3 += fmaxf(bhi(u.y) + ev.w, 0.f);
    }
    a0 += __shfl_xor(a0, 32); a1 += __shfl_xor(a1, 32);   // even-sum + odd-sum
    a2 += __shfl_xor(a2, 32); a3 += __shfl_xor(a3, 32);
    if (h == 0) {
        uint2 wv;
        wv.x = (unsigned int)f2b(a0) | ((unsigned int)f2b(a1) << 16);
        wv.y = (unsigned int)f2b(a2) | ((unsigned int)f2b(a3) << 16);
        *(uint2*)(aggb + (size_t)node * 128 + li * 4) = wv;
    }
}

// ---------------- fused GNN layer: x += LN(relu(agg@W1+b1)@W2+b2) ----------------
__global__ __launch_bounds__(512) void k_layer(const unsigned short* __restrict__ A,
                                               const unsigned short* __restrict__ W1T,
                                               const float* __restrict__ b1,
                                               const unsigned short* __restrict__ W2T,
                                               const float* __restrict__ b2,
                                               const float* __restrict__ lng,
                                               const float* __restrict__ lnb,
                                               float* __restrict__ x,
                                               unsigned short* __restrict__ xb) {
    __shared__ __align__(16) unsigned short WS[33792];     // 67.6 KB
    __shared__ __align__(16) unsigned short T[128][264];   // 67.6 KB
    int tid = threadIdx.x;
    int row0 = blockIdx.x * 128;
    int l = tid & 63, w = tid >> 6;
    int fr = l & 15, hi = l >> 4, fk = hi * 8;
    sh8 afr[4];
    #pragma unroll
    for (int kc = 0; kc < 4; kc++)
        afr[kc] = *(const sh8*)(A + (size_t)(row0 + w * 16 + fr) * 128 + kc * 32 + fk);
    #pragma unroll
    for (int s = tid; s < 4096; s += 512) {
        int n = s >> 4, k8 = s & 15;
        *(uint4*)&WS[n * 132 + k8 * 8] = *(const uint4*)(W1T + (size_t)n * 128 + k8 * 8);
    }
    __syncthreads();
    // ---- phase 1: T = relu(A @ W1 + b1), N=256 in 2 halves ----
    #pragma unroll
    for (int ch = 0; ch < 2; ch++) {
        f32x4 acc[8];
        #pragma unroll
        for (int c = 0; c < 8; c++) acc[c] = (f32x4){0.f, 0.f, 0.f, 0.f};
        #pragma unroll
        for (int kc = 0; kc < 4; kc++) {
            #pragma unroll
            for (int c = 0; c < 8; c++) {
                sh8 b = *(const sh8*)&WS[(ch * 128 + c * 16 + fr) * 132 + kc * 32 + fk];
                acc[c] = __builtin_amdgcn_mfma_f32_16x16x32_bf16(afr[kc], b, acc[c], 0, 0, 0);
            }
        }
        int rb = w * 16 + hi * 4;
        #pragma unroll
        for (int c = 0; c < 8; c++) {
            int col = ch * 128 + c * 16 + fr;
            float bv = b1[col];
            #pragma unroll
            for (int q = 0; q < 4; q++)
                T[rb + q][col] = f2b(fmaxf(acc[c][q] + bv, 0.f));
        }
    }
    __syncthreads();
    #pragma unroll
    for (int s = tid; s < 4096; s += 512) {
        int n = s >> 5, k8 = s & 31;
        *(uint4*)&WS[n * 264 + k8 * 8] = *(const uint4*)(W2T + (size_t)n * 256 + k8 * 8);
    }
    __syncthreads();
    // ---- phase 2: H = T @ W2 + b2 (K=256, N=128), LN, x += LN ----
    f32x4 acc[8];
    #pragma unroll
    for (int c = 0; c < 8; c++) acc[c] = (f32x4){0.f, 0.f, 0.f, 0.f};
    #pragma unroll 2
    for (int kc = 0; kc < 8; kc++) {
        sh8 a = *(const sh8*)&T[w * 16 + fr][kc * 32 + fk];
        #pragma unroll
        for (int c = 0; c < 8; c++) {
            sh8 b = *(const sh8*)&WS[(c * 16 + fr) * 264 + kc * 32 + fk];
            acc[c] = __builtin_amdgcn_mfma_f32_16x16x32_bf16(a, b, acc[c], 0, 0, 0);
        }
    }
    float s0 = 0.f, s1 = 0.f, s2 = 0.f, s3 = 0.f;
    float q0 = 0.f, q1 = 0.f, q2 = 0.f, q3 = 0.f;
    #pragma unroll
    for (int c = 0; c < 8; c++) {
        float bv = b2[c * 16 + fr];
        #pragma unroll
        for (int q = 0; q < 4; q++) acc[c][q] += bv;
        s0 += acc[c][0]; q0 += acc[c][0] * acc[c][0];
        s1 += acc[c][1]; q1 += acc[c][1] * acc[c][1];
        s2 += acc[c][2]; q2 += acc[c][2] * acc[c][2];
        s3 += acc[c][3]; q3 += acc[c][3] * acc[c][3];
    }
    #pragma unroll
    for (int m = 1; m < 16; m <<= 1) {
        s0 += __shfl_xor(s0, m); q0 += __shfl_xor(q0, m);
        s1 += __shfl_xor(s1, m); q1 += __shfl_xor(q1, m);
        s2 += __shfl_xor(s2, m); q2 += __shfl_xor(q2, m);
        s3 += __shfl_xor(s3, m); q3 += __shfl_xor(q3, m);
    }
    float mu[4], rs_[4];
    mu[0] = s0 * (1.f / 128.f); rs_[0] = rsqrtf(q0 * (1.f / 128.f) - mu[0] * mu[0] + 1e-5f);
    mu[1] = s1 * (1.f / 128.f); rs_[1] = rsqrtf(q1 * (1.f / 128.f) - mu[1] * mu[1] + 1e-5f);
    mu[2] = s2 * (1.f / 128.f); rs_[2] = rsqrtf(q2 * (1.f / 128.f) - mu[2] * mu[2] + 1e-5f);
    mu[3] = s3 * (1.f / 128.f); rs_[3] = rsqrtf(q3 * (1.f / 128.f) - mu[3] * mu[3] + 1e-5f);
    int rbase = row0 + w * 16 + hi * 4;
    #pragma unroll
    for (int c = 0; c < 8; c++) {
        int col = c * 16 + fr;
        float g = lng[col], bb = lnb[col];
        #pragma unroll
        for (int q = 0; q < 4; q++) {
            size_t idx = (size_t)(rbase + q) * 128 + col;
            float nx = x[idx] + (acc[c][q] - mu[q]) * rs_[q] * g + bb;
            x[idx] = nx;
            xb[idx] = f2b(nx);
        }
    }
}

// ---------------- fused gate (T-free) + softmax + pooling + residual blocks + head ----------------
// Block covers 128 node rows = 2 complete graphs. Phase A: register-resident gate
// GEMM+LN(256)+relu+dot (validated r10/12). Phase B: per-graph softmax + weighted
// pooling (validated r10/12). Phase C: per-graph 2 residual blocks + head — lifted
// verbatim from round-8's k_gpt phase C (correctness-validated there; its slowness
// was the 138KB-LDS structure, absent here). LDS total 69.3 KB -> 2 blocks/CU.
// Saves the separate k_tail launch + gpool round-trip.
__global__ __launch_bounds__(512) void k_gatepool(const unsigned short* __restrict__ xbin,
        const float* __restrict__ xf,
        const unsigned short* __restrict__ gW1T,
        const float* __restrict__ b1,
        const float* __restrict__ lng, const float* __restrict__ lnb,
        const float* __restrict__ w2, const float* __restrict__ b2,
        const float* __restrict__ fc1W, const float* __restrict__ fc1b,
        const float* __restrict__ ln1g, const float* __restrict__ ln1b,
        const float* __restrict__ fc2W, const float* __restrict__ fc2b,
        const float* __restrict__ ln2g, const float* __restrict__ ln2b,
        const float* __restrict__ pW1, const float* __restrict__ pb1,
        const float* __restrict__ pW2, const float* __restrict__ pb2,
        float* __restrict__ out) {
    __shared__ __align__(16) unsigned short WS[33792];
    __shared__ float gates[128];
    __shared__ float pooled[2][128];
    __shared__ float shh[2][128];
    __shared__ float ps[2][2], pq[2][2];
    int tid = threadIdx.x;
    int row0 = blockIdx.x * 128;
    int l = tid & 63, w = tid >> 6;
    int fr = l & 15, hi = l >> 4, fk = hi * 8;
    // ---- phase A: register-resident gate ----
    sh8 afr[4];
    #pragma unroll
    for (int kc = 0; kc < 4; kc++)
        afr[kc] = *(const sh8*)(xbin + (size_t)(row0 + w * 16 + fr) * 128 + kc * 32 + fk);
    #pragma unroll
    for (int s = tid; s < 4096; s += 512) {
        int n = s >> 4, k8 = s & 15;
        *(uint4*)&WS[n * 132 + k8 * 8] = *(const uint4*)(gW1T + (size_t)n * 128 + k8 * 8);
    }
    __syncthreads();
    f32x4 acc[2][8];
    #pragma unroll
    for (int ch = 0; ch < 2; ch++)
        #pragma unroll
        for (int c = 0; c < 8; c++) acc[ch][c] = (f32x4){0.f, 0.f, 0.f, 0.f};
    #pragma unroll
    for (int kc = 0; kc < 4; kc++) {
        #pragma unroll
        for (int ch = 0; ch < 2; ch++) {
            #pragma unroll
            for (int c = 0; c < 8; c++) {
                sh8 b = *(const sh8*)&WS[(ch * 128 + c * 16 + fr) * 132 + kc * 32 + fk];
                acc[ch][c] = __builtin_amdgcn_mfma_f32_16x16x32_bf16(afr[kc], b, acc[ch][c], 0, 0, 0);
            }
        }
    }
    float s[4] = {0.f, 0.f, 0.f, 0.f}, q[4] = {0.f, 0.f, 0.f, 0.f};
    #pragma unroll
    for (int ch = 0; ch < 2; ch++) {
        #pragma unroll
        for (int c = 0; c < 8; c++) {
            float bv = b1[ch * 128 + c * 16 + fr];
            #pragma unroll
            for (int qd = 0; qd < 4; qd++) {
                float v = acc[ch][c][qd] + bv;
                acc[ch][c][qd] = v;
                s[qd] += v; q[qd] += v * v;
            }
        }
    }
    #pragma unroll
    for (int m = 1; m < 16; m <<= 1) {
        #pragma unroll
        for (int qd = 0; qd < 4; qd++) {
            s[qd] += __shfl_xor(s[qd], m);
            q[qd] += __shfl_xor(q[qd], m);
        }
    }
    float mu[4], rcp[4];
    #pragma unroll
    for (int qd = 0; qd < 4; qd++) {
        mu[qd] = s[qd] * (1.f / 256.f);
        rcp[qd] = rsqrtf(q[qd] * (1.f / 256.f) - mu[qd] * mu[qd] + 1e-5f);
    }
    float dot[4] = {0.f, 0.f, 0.f, 0.f};
    #pragma unroll
    for (int ch = 0; ch < 2; ch++) {
        #pragma unroll
        for (int c = 0; c < 8; c++) {
            int col = ch * 128 + c * 16 + fr;
            float g = lng[col], bb = lnb[col], ww = w2[col];
            #pragma unroll
            for (int qd = 0; qd < 4; qd++) {
                float z = (acc[ch][c][qd] - mu[qd]) * rcp[qd] * g + bb;
                dot[qd] += fmaxf(z, 0.f) * ww;
            }
        }
    }
    #pragma unroll
    for (int m = 1; m < 16; m <<= 1)
        #pragma unroll
        for (int qd = 0; qd < 4; qd++) dot[qd] += __shfl_xor(dot[qd], m);
    if (fr == 0) {
        float b2v = b2[0];
        #pragma unroll
        for (int qd = 0; qd < 4; qd++)
            gates[w * 16 + hi * 4 + qd] = dot[qd] + b2v;
    }
    __syncthreads();
    // ---- phase B: softmax + pooling; graph group g = tid>>8 ----
    int g = tid >> 8, t2 = tid & 255;
    if (t2 < 64) {   // one full wave per graph (tid 0-63 / 256-319)
        float gv = gates[g * 64 + t2];
        float m = gv;
        #pragma unroll
        for (int mk = 1; mk < 64; mk <<= 1) m = fmaxf(m, __shfl_xor(m, mk));
        float e = expf(gv - m);
        float ss = e;
        #pragma unroll
        for (int mk = 1; mk < 64; mk <<= 1) ss += __shfl_xor(ss, mk);
        gates[g * 64 + t2] = e / ss;
    }
    __syncthreads();
    int d = t2 & 127, hh = t2 >> 7;
    float pacc = 0.f;
    for (int i = hh * 32; i < hh * 32 + 32; i++)
        pacc += gates[g * 64 + i] * xf[(size_t)(row0 + g * 64 + i) * 128 + d];
    if (hh == 0) pooled[g][d] = pacc;
    __syncthreads();
    if (hh == 1) pooled[g][d] += pacc;
    __syncthreads();
    // ---- phase C: residual blocks + head (round-8 validated code) ----
    int wv = t2 >> 6;
    for (int r = 0; r < 2; r++) {
        float acc1 = 0.f, sr = 0.f, qr = 0.f;
        if (t2 < 128) {
            const float* W1 = fc1W + r * 16384;
            acc1 = fc1b[r * 128 + t2];
            for (int k = 0; k < 128; k++) acc1 += pooled[g][k] * W1[k * 128 + t2];
            sr = acc1; qr = acc1 * acc1;
            #pragma unroll
            for (int m = 1; m < 64; m <<= 1) { sr += __shfl_xor(sr, m); qr += __shfl_xor(qr, m); }
            if ((t2 & 63) == 0) { ps[g][wv] = sr; pq[g][wv] = qr; }
        }
        __syncthreads();
        if (t2 < 128) {
            float S = ps[g][0] + ps[g][1], Q = pq[g][0] + pq[g][1];
            float mu1 = S * (1.f / 128.f);
            float var = Q * (1.f / 128.f) - mu1 * mu1;
            float z = (acc1 - mu1) * rsqrtf(var + 1e-5f) * ln1g[r * 128 + t2] + ln1b[r * 128 + t2];
            shh[g][t2] = gelu_exact(z);
        }
        __syncthreads();
        float acc2 = 0.f;
        if (t2 < 128) {
            const float* W2 = fc2W + r * 16384;
            acc2 = fc2b[r * 128 + t2];
            for (int k = 0; k < 128; k++) acc2 += shh[g][k] * W2[k * 128 + t2];
            sr = acc2; qr = acc2 * acc2;
            #pragma unroll
            for (int m = 1; m < 64; m <<= 1) { sr += __shfl_xor(sr, m); qr += __shfl_xor(qr, m); }
            if ((t2 & 63) == 0) { ps[g][wv] = sr; pq[g][wv] = qr; }
        }
        __syncthreads();
        if (t2 < 128) {
            float S = ps[g][0] + ps[g][1], Q = pq[g][0] + pq[g][1];
            float mu1 = S * (1.f / 128.f);
            float var = Q * (1.f / 128.f) - mu1 * mu1;
            float z2 = (acc2 - mu1) * rsqrtf(var + 1e-5f) * ln2g[r * 128 + t2] + ln2b[r * 128 + t2];
            pooled[g][t2] = pooled[g][t2] + z2;
        }
        __syncthreads();
    }
    float hacc = 0.f;
    if (t2 < 128) {
        hacc = pb1[t2];
        for (int k = 0; k < 128; k++) hacc += pooled[g][k] * pW1[k * 128 + t2];
    }
    __syncthreads();
    if (t2 < 128) shh[g][t2] = gelu_exact(hacc);
    __syncthreads();
    if (t2 < 12) {
        float o = pb2[t2];
        for (int k = 0; k < 128; k++) o += shh[g][k] * pW2[k * 12 + t2];
        out[(size_t)(blockIdx.x * 2 + g) * 12 + t2] = o;
    }
}

// ---------------- launch ----------------
extern "C" void kernel_launch(void* const* d_in, const int* in_sizes, int n_in,
                              void* d_out, int out_size, void* d_ws, size_t ws_size,
                              hipStream_t stream) {
    const float* logits    = (const float*)d_in[0];
    const int*   atom_feat = (const int*)d_in[2];
    const int*   edge_src  = (const int*)d_in[3];
    const int*   edge_dst  = edge_src + N_EDGES;
    const int*   edge_attr = (const int*)d_in[4];
    const float* atom_emb  = (const float*)d_in[6];
    const float* edge_emb  = (const float*)d_in[7];
    const float* gnn_W1    = (const float*)d_in[8];
    const float* gnn_b1    = (const float*)d_in[9];
    const float* gnn_W2    = (const float*)d_in[10];
    const float* gnn_b2    = (const float*)d_in[11];
    const float* gnn_ln_g  = (const float*)d_in[12];
    const float* gnn_ln_b  = (const float*)d_in[13];
    const float* gate_W1   = (const float*)d_in[14];
    const float* gate_b1   = (const float*)d_in[15];
    const float* gate_ln_g = (const float*)d_in[16];
    const float* gate_ln_b = (const float*)d_in[17];
    const float* gate_W2   = (const float*)d_in[18];
    const float* gate_b2   = (const float*)d_in[19];
    const float* res_fc1_W = (const float*)d_in[20];
    const float* res_fc1_b = (const float*)d_in[21];
    const float* res_ln1_g = (const float*)d_in[22];
    const float* res_ln1_b = (const float*)d_in[23];
    const float* res_fc2_W = (const float*)d_in[24];
    const float* res_fc2_b = (const float*)d_in[25];
    const float* res_ln2_g = (const float*)d_in[26];
    const float* res_ln2_b = (const float*)d_in[27];
    const float* pred_W1   = (const float*)d_in[28];
    const float* pred_b1   = (const float*)d_in[29];
    const float* pred_W2   = (const float*)d_in[30];
    const float* pred_b2   = (const float*)d_in[31];
    float* out = (float*)d_out;

    char* w = (char*)d_ws;
    float*          x    = (float*)w;          w += (size_t)N_NODES * 128 * 4;  // 16 MB fp32 master
    unsigned short* xb   = (unsigned short*)w; w += (size_t)N_NODES * 128 * 2;  // 8 MB bf16 shadow
    unsigned short* aggb = (unsigned short*)w; w += (size_t)N_NODES * 128 * 2;  // 8 MB
    unsigned short* W1T  = (unsigned short*)w; w += 3 * 32768 * 2;
    unsigned short* W2T  = (unsigned short*)w; w += 3 * 32768 * 2;
    unsigned short* gW1T = (unsigned short*)w; w += 32768 * 2;
    int*   deg    = (int*)w;   w += N_NODES * 4;
    int*   offs   = (int*)w;   w += (N_NODES + 64) * 4;
    int*   cursor = (int*)w;   w += N_NODES * 4;
    int*   csr    = (int*)w;   w += N_EDGES * 4;

    // fused prep (weights + deg zero + build_x), then CSR build
    k_prep<<<PREP_BLOCKS + BX_BLOCKS, 256, 0, stream>>>(
        gnn_W1, gnn_W2, gate_W1, logits, atom_feat, atom_emb,
        W1T, W2T, gW1T, deg, x, xb);
    k_deg<<<N_EDGES / 256, 256, 0, stream>>>(edge_dst, deg);
    k_scan<<<1, 1024, 0, stream>>>(deg, offs, cursor);
    k_scatter<<<N_EDGES / 256, 256, 0, stream>>>(edge_src, edge_dst, edge_attr, cursor, csr);

    // 3 GNN layers: full-width aggregation + fused MLP+LN+residual
    for (int l = 0; l < 3; l++) {
        k_agg<<<N_NODES / 4, 256, 0, stream>>>(xb, offs, csr, edge_emb, aggb);
        k_layer<<<N_NODES / 128, 512, 0, stream>>>(
            aggb, W1T + l * 32768, gnn_b1 + l * 256,
            W2T + l * 32768, gnn_b2 + l * 128,
            gnn_ln_g + l * 128, gnn_ln_b + l * 128, x, xb);
    }

    // fused gate + softmax + pooling + residual blocks + head
    k_gatepool<<<N_NODES / 128, 512, 0, stream>>>(
        xb, x, gW1T, gate_b1, gate_ln_g, gate_ln_b, gate_W2, gate_b2,
        res_fc1_W, res_fc1_b, res_ln1_g, res_ln1_b,
        res_fc2_W, res_fc2_b, res_ln2_g, res_ln2_b,
        pred_W1, pred_b1, pred_W2, pred_b2, out);
}